// Round 10
// baseline (463.113 us; speedup 1.0000x reference)
//
#include <hip/hip_runtime.h>

#define DIM 128
#define EPS 1e-5f
#define RPB 256            // rows per pool block

typedef short  bf16x8 __attribute__((ext_vector_type(8)));
typedef float  f32x2  __attribute__((ext_vector_type(2)));
typedef float  f32x4  __attribute__((ext_vector_type(4)));

__device__ __forceinline__ unsigned short f2b(float f) {
    unsigned int u = __builtin_bit_cast(unsigned int, f);
    unsigned int r = (u + 0x7FFFu + ((u >> 16) & 1u)) >> 16;   // RNE
    return (unsigned short)r;
}
__device__ __forceinline__ bf16x8 ldw8(const float* __restrict__ p) {
    f32x4 a = *reinterpret_cast<const f32x4*>(p);
    f32x4 b = *reinterpret_cast<const f32x4*>(p + 4);
    bf16x8 r;
    #pragma unroll
    for (int j = 0; j < 4; ++j) {
        r[j]     = (short)f2b(a[j]);
        r[j + 4] = (short)f2b(b[j]);
    }
    return r;
}

// ---------------------------------------------------------------------------
// K0a: zero the 4 MB f32 segment-sum accumulator (lives in h_out region,
// which k_add overwrites at the very end). Re-zeroed every call.
// ---------------------------------------------------------------------------
__global__ __launch_bounds__(256) void k_zero(float* __restrict__ accum)
{
    const int i = blockIdx.x * blockDim.x + threadIdx.x;   // 0..262143
    *reinterpret_cast<f32x4*>(accum + (size_t)i * 4) = (f32x4){0.f, 0.f, 0.f, 0.f};
}

// ---------------------------------------------------------------------------
// K0b: segment boundaries. bounds[b] = first n with batch[n] >= b.
// ---------------------------------------------------------------------------
__global__ __launch_bounds__(256) void k_bounds(
    const int* __restrict__ batch, int* __restrict__ bounds, int n_nodes, int nb)
{
    const int idx = blockIdx.x * blockDim.x + threadIdx.x;
    if (idx > n_nodes) return;
    const int cur  = (idx < n_nodes) ? batch[idx] : nb;
    const int prev = (idx > 0) ? batch[idx - 1] : -1;
    for (int b = prev + 1; b <= cur; ++b) bounds[b] = idx;
}

// ---------------------------------------------------------------------------
// K1: LINEAR segment-sum. Block owns 256 contiguous rows (128 KB slab);
// all resident blocks sweep the address space together like k_add.
// Each wave owns 64 consecutive rows (FIXED from round 9: was 32, dropping
// half the slab). Per-row: f32x2/lane (512 B coalesced), LDS-atomic adds
// into a 32-graph local accumulator, then one global atomicAdd flush per
// spanned graph. ~17 KB LDS -> 8 blocks/CU (wave-capped).
// ---------------------------------------------------------------------------
__global__ __launch_bounds__(256) void k_pool_lin(
    const float* __restrict__ h, const int* __restrict__ batch,
    float* __restrict__ accum, int n_nodes)
{
    __shared__ float acc[32][DIM];     // 16 KB
    __shared__ int   sbat[RPB];

    const int tid = threadIdx.x;
    const int r0  = blockIdx.x * RPB;

    float* af = &acc[0][0];
    #pragma unroll
    for (int i = 0; i < 16; ++i) af[tid + 256 * i] = 0.f;

    const int rend = min(RPB, n_nodes - r0);
    if (tid < rend) sbat[tid] = batch[r0 + tid];
    __syncthreads();

    const int g0   = sbat[0];
    const int wave = tid >> 6, lane = tid & 63;
    const int lr_beg = wave * 64;                  // 4 waves x 64 = 256 rows
    const int lr_end = min(lr_beg + 64, rend);

    #pragma unroll 4
    for (int lr = lr_beg; lr < lr_end; ++lr) {
        f32x2 v = *reinterpret_cast<const f32x2*>(
            h + (size_t)(r0 + lr) * DIM + lane * 2);
        const int gl = sbat[lr] - g0;
        if (gl < 32) {
            atomicAdd(&acc[gl][lane * 2],     v[0]);
            atomicAdd(&acc[gl][lane * 2 + 1], v[1]);
        } else {   // pathological tiny-segment slab: direct global
            atomicAdd(&accum[(size_t)(g0 + gl) * DIM + lane * 2],     v[0]);
            atomicAdd(&accum[(size_t)(g0 + gl) * DIM + lane * 2 + 1], v[1]);
        }
    }
    __syncthreads();

    int gspan = sbat[rend - 1] - g0 + 1;
    if (gspan > 32) gspan = 32;
    for (int idx = tid; idx < (gspan << 7); idx += 256) {
        const int gl = idx >> 7, c = idx & 127;
        const float v = acc[gl][c];
        if (v != 0.f) atomicAdd(&accum[(size_t)(g0 + gl) * DIM + c], v);
    }
}

// ---------------------------------------------------------------------------
// K2: vn MLP with inlined finish: x = accum*inv + vn_h (f32 -> bf16), then
// Linear->LN->ReLU->Linear via MFMA 16x16x32. One wave per 16 graphs.
// A/B share the element->k bijection -> k-permutation safe.
// C/D (m89-verified): col n = lane&15, row m = (lane>>4)*4 + reg.
// ---------------------------------------------------------------------------
__global__ __launch_bounds__(256) void k_mlp(
    const float* __restrict__ accum, const int* __restrict__ bounds,
    const float* __restrict__ vn,
    const float* __restrict__ W1, const float* __restrict__ b1,
    const float* __restrict__ lng, const float* __restrict__ lnb,
    const float* __restrict__ W2, const float* __restrict__ b2v,
    float* __restrict__ vn_out)
{
    __shared__ unsigned short zt[4][16][136];

    const int wave  = threadIdx.x >> 6;
    const int lane  = threadIdx.x & 63;
    const int gtile = blockIdx.x * 4 + wave;
    const int row16 = lane & 15;
    const int kgrp  = lane >> 4;

    const int g   = gtile * 16 + row16;
    const int cnt = bounds[g + 1] - bounds[g];
    const float inv = 1.0f / (float)(cnt > 1 ? cnt : 1);

    bf16x8 afrag[4];
    #pragma unroll
    for (int kk = 0; kk < 4; ++kk) {
        const float* ap = accum + (size_t)g * DIM + kgrp * 8 + kk * 32;
        const float* vp = vn    + (size_t)g * DIM + kgrp * 8 + kk * 32;
        f32x4 s0 = *reinterpret_cast<const f32x4*>(ap);
        f32x4 s1 = *reinterpret_cast<const f32x4*>(ap + 4);
        f32x4 u0 = *reinterpret_cast<const f32x4*>(vp);
        f32x4 u1 = *reinterpret_cast<const f32x4*>(vp + 4);
        #pragma unroll
        for (int j = 0; j < 4; ++j) {
            afrag[kk][j]     = (short)f2b(fmaf(s0[j], inv, u0[j]));
            afrag[kk][j + 4] = (short)f2b(fmaf(s1[j], inv, u1[j]));
        }
    }

    f32x4 acc[8];
    #pragma unroll
    for (int t = 0; t < 8; ++t) acc[t] = (f32x4){0.f, 0.f, 0.f, 0.f};
    #pragma unroll
    for (int t = 0; t < 8; ++t) {
        const float* wp = W1 + (size_t)(t * 16 + row16) * DIM + kgrp * 8;
        #pragma unroll
        for (int kk = 0; kk < 4; ++kk) {
            bf16x8 bfrag = ldw8(wp + kk * 32);
            acc[t] = __builtin_amdgcn_mfma_f32_16x16x32_bf16(afrag[kk], bfrag, acc[t], 0, 0, 0);
        }
    }

    float b1f[8], gf[8], bf_[8], b2f8[8];
    #pragma unroll
    for (int t = 0; t < 8; ++t) {
        const int f = t * 16 + row16;
        b1f[t]  = b1[f];
        gf[t]   = lng[f];
        bf_[t]  = lnb[f];
        b2f8[t] = b2v[f];
    }
    #pragma unroll
    for (int t = 0; t < 8; ++t)
        #pragma unroll
        for (int r = 0; r < 4; ++r) acc[t][r] += b1f[t];

    #pragma unroll
    for (int r = 0; r < 4; ++r) {
        float sm = 0.f, ss = 0.f;
        #pragma unroll
        for (int t = 0; t < 8; ++t) { sm += acc[t][r]; ss += acc[t][r] * acc[t][r]; }
        #pragma unroll
        for (int m = 1; m <= 8; m <<= 1) {
            sm += __shfl_xor(sm, m);
            ss += __shfl_xor(ss, m);
        }
        const float mu  = sm * (1.0f / 128.0f);
        const float var = ss * (1.0f / 128.0f) - mu * mu;
        const float rs  = rsqrtf(var + EPS);
        const int   gm  = kgrp * 4 + r;
        #pragma unroll
        for (int t = 0; t < 8; ++t) {
            float z = (acc[t][r] - mu) * rs * gf[t] + bf_[t];
            z = fmaxf(z, 0.f);
            zt[wave][gm][t * 16 + row16] = f2b(z);
        }
    }
    __syncthreads();

    bf16x8 afrag2[4];
    #pragma unroll
    for (int kk = 0; kk < 4; ++kk)
        afrag2[kk] = *reinterpret_cast<const bf16x8*>(&zt[wave][row16][kk * 32 + kgrp * 8]);

    f32x4 acc2[8];
    #pragma unroll
    for (int t = 0; t < 8; ++t) acc2[t] = (f32x4){0.f, 0.f, 0.f, 0.f};
    #pragma unroll
    for (int t = 0; t < 8; ++t) {
        const float* wp = W2 + (size_t)(t * 16 + row16) * DIM + kgrp * 8;
        #pragma unroll
        for (int kk = 0; kk < 4; ++kk) {
            bf16x8 bfrag = ldw8(wp + kk * 32);
            acc2[t] = __builtin_amdgcn_mfma_f32_16x16x32_bf16(afrag2[kk], bfrag, acc2[t], 0, 0, 0);
        }
    }

    #pragma unroll
    for (int r = 0; r < 4; ++r) {
        float* op = vn_out + (size_t)(gtile * 16 + kgrp * 4 + r) * DIM + row16;
        #pragma unroll
        for (int t = 0; t < 8; ++t)
            op[t * 16] = acc2[t][r] + b2f8[t];
    }
}

// ---------------------------------------------------------------------------
// K3: h_out = h + vn_out[batch], REVERSED window sweep. After k_pool_lin's
// ascending sweep, L3 holds the tail of h; reading tail-first converts the
// LRU wrap-around (miss-everything) into hit-most. NT stores keep the write
// stream from evicting h.
// ---------------------------------------------------------------------------
__global__ __launch_bounds__(256) void k_add(
    const float* __restrict__ h, const int* __restrict__ batch,
    const float* __restrict__ vn_out, float* __restrict__ h_out,
    int n_nodes)
{
    const long total = (long)n_nodes * 16;     // 16 8-float units per row
    const long GS    = (long)gridDim.x * blockDim.x;
    const long gtid  = (long)blockIdx.x * blockDim.x + threadIdx.x;
    for (long base = ((total + GS - 1) / GS - 1) * GS; base >= 0; base -= GS) {
        const long u = base + gtid;
        if (u >= total) continue;
        const int n = (int)(u >> 4);
        const int c = ((int)u & 15) * 8;
        const float* hp = h + (size_t)n * DIM + c;
        f32x4 h0 = *reinterpret_cast<const f32x4*>(hp);
        f32x4 h1 = *reinterpret_cast<const f32x4*>(hp + 4);
        const int b = batch[n];
        const float* vp = vn_out + (size_t)b * DIM + c;
        f32x4 v0 = *reinterpret_cast<const f32x4*>(vp);
        f32x4 v1 = *reinterpret_cast<const f32x4*>(vp + 4);
        float* op = h_out + (size_t)n * DIM + c;
        __builtin_nontemporal_store(h0 + v0, reinterpret_cast<f32x4*>(op));
        __builtin_nontemporal_store(h1 + v1, reinterpret_cast<f32x4*>(op + 4));
    }
}

// ---------------------------------------------------------------------------
extern "C" void kernel_launch(void* const* d_in, const int* in_sizes, int n_in,
                              void* d_out, int out_size, void* d_ws, size_t ws_size,
                              hipStream_t stream)
{
    const float* h    = (const float*)d_in[0];
    const int*   bat  = (const int*)d_in[1];
    const float* vn   = (const float*)d_in[2];
    const float* W1   = (const float*)d_in[3];
    const float* b1   = (const float*)d_in[4];
    const float* lng  = (const float*)d_in[5];
    const float* lnb  = (const float*)d_in[6];
    const float* W2   = (const float*)d_in[7];
    const float* b2v  = (const float*)d_in[8];

    const int n_nodes = in_sizes[0] / DIM;   // 500000
    const int nb      = in_sizes[2] / DIM;   // 8192

    float* out    = (float*)d_out;           // f32 output buffer
    float* h_out  = out;
    float* vn_out = out + (size_t)n_nodes * DIM;
    float* accum  = out;                     // 4 MB scratch in h_out region
    int*   bounds = (int*)d_ws;              // (nb+1) ints

    k_zero<<<(nb * DIM) / 1024, 256, 0, stream>>>(accum);
    k_bounds<<<(n_nodes + 256) / 256, 256, 0, stream>>>(bat, bounds, n_nodes, nb);
    k_pool_lin<<<(n_nodes + RPB - 1) / RPB, 256, 0, stream>>>(h, bat, accum, n_nodes);
    k_mlp<<<nb / 64, 256, 0, stream>>>(accum, bounds, vn, W1, b1, lng, lnb,
                                       W2, b2v, vn_out);
    k_add<<<2048, 256, 0, stream>>>(h, bat, vn_out, h_out, n_nodes);
}

// Round 11
// 193.794 us; speedup vs baseline: 2.3897x; 2.3897x over previous
//
#include <hip/hip_runtime.h>

#define DIM 128
#define EPS 1e-5f

typedef short  bf16x8 __attribute__((ext_vector_type(8)));
typedef float  f32x2  __attribute__((ext_vector_type(2)));
typedef float  f32x4  __attribute__((ext_vector_type(4)));

__device__ __forceinline__ unsigned short f2b(float f) {
    unsigned int u = __builtin_bit_cast(unsigned int, f);
    unsigned int r = (u + 0x7FFFu + ((u >> 16) & 1u)) >> 16;   // RNE
    return (unsigned short)r;
}
__device__ __forceinline__ bf16x8 ldw8(const float* __restrict__ p) {
    f32x4 a = *reinterpret_cast<const f32x4*>(p);
    f32x4 b = *reinterpret_cast<const f32x4*>(p + 4);
    bf16x8 r;
    #pragma unroll
    for (int j = 0; j < 4; ++j) {
        r[j]     = (short)f2b(a[j]);
        r[j + 4] = (short)f2b(b[j]);
    }
    return r;
}

// ---------------------------------------------------------------------------
// K0a: zero the 4 MB f32 segment-sum accumulator (lives in h_out region,
// which k_add overwrites at the very end). Re-zeroed every call.
// ---------------------------------------------------------------------------
__global__ __launch_bounds__(256) void k_zero(float* __restrict__ accum)
{
    const int i = blockIdx.x * blockDim.x + threadIdx.x;
    *reinterpret_cast<f32x4*>(accum + (size_t)i * 4) = (f32x4){0.f, 0.f, 0.f, 0.f};
}

// ---------------------------------------------------------------------------
// K0b: segment boundaries. bounds[b] = first n with batch[n] >= b.
// ---------------------------------------------------------------------------
__global__ __launch_bounds__(256) void k_bounds(
    const int* __restrict__ batch, int* __restrict__ bounds, int n_nodes, int nb)
{
    const int idx = blockIdx.x * blockDim.x + threadIdx.x;
    if (idx > n_nodes) return;
    const int cur  = (idx < n_nodes) ? batch[idx] : nb;
    const int prev = (idx > 0) ? batch[idx - 1] : -1;
    for (int b = prev + 1; b <= cur; ++b) bounds[b] = idx;
}

// ---------------------------------------------------------------------------
// K1: NARROW-WINDOW segment-sum. Grid-stride by WAVE over 16-row units
// (8 KB each): all resident waves work inside one ~32 MB sliding window
// (the fillBuffer access shape), unlike block-owns-slab which spreads the
// footprint over the whole array. No LDS atomics (round-10 killer).
// A unit is almost always one graph (avg segment 61 rows): register
// accumulate, then 2 global f32 atomicAdds per lane into the L3-resident
// 4 MB accum. Boundary units take the per-row run-flush path.
// ---------------------------------------------------------------------------
__global__ __launch_bounds__(256) void k_pool_ns(
    const float* __restrict__ h, const int* __restrict__ batch,
    float* __restrict__ accum, int n_nodes)
{
    const int nwaves = gridDim.x * (blockDim.x >> 6);
    const int w      = (blockIdx.x * blockDim.x + threadIdx.x) >> 6;
    const int lane   = threadIdx.x & 63;
    const int U      = (n_nodes + 15) >> 4;

    for (int u = w; u < U; u += nwaves) {
        const int r0 = u << 4;
        const int r1 = min(r0 + 16, n_nodes);
        const int bfirst = batch[r0];
        const int blast  = batch[r1 - 1];
        const float* p = h + (size_t)r0 * DIM + lane * 2;

        if (bfirst == blast) {
            // fast path: whole unit in one graph; 4 rotating accumulators
            f32x2 a0 = (f32x2){0.f, 0.f}, a1 = a0, a2 = a0, a3 = a0;
            const int cr = r1 - r0;
            int r = 0;
            for (; r + 4 <= cr; r += 4) {
                a0 += *reinterpret_cast<const f32x2*>(p + (size_t)(r + 0) * DIM);
                a1 += *reinterpret_cast<const f32x2*>(p + (size_t)(r + 1) * DIM);
                a2 += *reinterpret_cast<const f32x2*>(p + (size_t)(r + 2) * DIM);
                a3 += *reinterpret_cast<const f32x2*>(p + (size_t)(r + 3) * DIM);
            }
            for (; r < cr; ++r)
                a0 += *reinterpret_cast<const f32x2*>(p + (size_t)r * DIM);
            a0 += a1; a2 += a3; a0 += a2;
            float* d = accum + (size_t)bfirst * DIM + lane * 2;
            atomicAdd(d,     a0[0]);
            atomicAdd(d + 1, a0[1]);
        } else {
            // boundary unit: run-flush on graph change
            int cur = bfirst;
            f32x2 a = (f32x2){0.f, 0.f};
            for (int r = r0; r < r1; ++r) {
                const int b = batch[r];
                if (b != cur) {
                    float* d = accum + (size_t)cur * DIM + lane * 2;
                    atomicAdd(d,     a[0]);
                    atomicAdd(d + 1, a[1]);
                    a = (f32x2){0.f, 0.f};
                    cur = b;
                }
                a += *reinterpret_cast<const f32x2*>(
                    h + (size_t)r * DIM + lane * 2);
            }
            float* d = accum + (size_t)cur * DIM + lane * 2;
            atomicAdd(d,     a[0]);
            atomicAdd(d + 1, a[1]);
        }
    }
}

// ---------------------------------------------------------------------------
// K2: vn MLP with inlined finish: x = accum*inv + vn_h (f32 -> bf16), then
// Linear->LN->ReLU->Linear via MFMA 16x16x32. One wave per 16 graphs.
// (passed correctness in round 10; unchanged)
// ---------------------------------------------------------------------------
__global__ __launch_bounds__(256) void k_mlp(
    const float* __restrict__ accum, const int* __restrict__ bounds,
    const float* __restrict__ vn,
    const float* __restrict__ W1, const float* __restrict__ b1,
    const float* __restrict__ lng, const float* __restrict__ lnb,
    const float* __restrict__ W2, const float* __restrict__ b2v,
    float* __restrict__ vn_out)
{
    __shared__ unsigned short zt[4][16][136];

    const int wave  = threadIdx.x >> 6;
    const int lane  = threadIdx.x & 63;
    const int gtile = blockIdx.x * 4 + wave;
    const int row16 = lane & 15;
    const int kgrp  = lane >> 4;

    const int g   = gtile * 16 + row16;
    const int cnt = bounds[g + 1] - bounds[g];
    const float inv = 1.0f / (float)(cnt > 1 ? cnt : 1);

    bf16x8 afrag[4];
    #pragma unroll
    for (int kk = 0; kk < 4; ++kk) {
        const float* ap = accum + (size_t)g * DIM + kgrp * 8 + kk * 32;
        const float* vp = vn    + (size_t)g * DIM + kgrp * 8 + kk * 32;
        f32x4 s0 = *reinterpret_cast<const f32x4*>(ap);
        f32x4 s1 = *reinterpret_cast<const f32x4*>(ap + 4);
        f32x4 u0 = *reinterpret_cast<const f32x4*>(vp);
        f32x4 u1 = *reinterpret_cast<const f32x4*>(vp + 4);
        #pragma unroll
        for (int j = 0; j < 4; ++j) {
            afrag[kk][j]     = (short)f2b(fmaf(s0[j], inv, u0[j]));
            afrag[kk][j + 4] = (short)f2b(fmaf(s1[j], inv, u1[j]));
        }
    }

    f32x4 acc[8];
    #pragma unroll
    for (int t = 0; t < 8; ++t) acc[t] = (f32x4){0.f, 0.f, 0.f, 0.f};
    #pragma unroll
    for (int t = 0; t < 8; ++t) {
        const float* wp = W1 + (size_t)(t * 16 + row16) * DIM + kgrp * 8;
        #pragma unroll
        for (int kk = 0; kk < 4; ++kk) {
            bf16x8 bfrag = ldw8(wp + kk * 32);
            acc[t] = __builtin_amdgcn_mfma_f32_16x16x32_bf16(afrag[kk], bfrag, acc[t], 0, 0, 0);
        }
    }

    float b1f[8], gf[8], bf_[8], b2f8[8];
    #pragma unroll
    for (int t = 0; t < 8; ++t) {
        const int f = t * 16 + row16;
        b1f[t]  = b1[f];
        gf[t]   = lng[f];
        bf_[t]  = lnb[f];
        b2f8[t] = b2v[f];
    }
    #pragma unroll
    for (int t = 0; t < 8; ++t)
        #pragma unroll
        for (int r = 0; r < 4; ++r) acc[t][r] += b1f[t];

    #pragma unroll
    for (int r = 0; r < 4; ++r) {
        float sm = 0.f, ss = 0.f;
        #pragma unroll
        for (int t = 0; t < 8; ++t) { sm += acc[t][r]; ss += acc[t][r] * acc[t][r]; }
        #pragma unroll
        for (int m = 1; m <= 8; m <<= 1) {
            sm += __shfl_xor(sm, m);
            ss += __shfl_xor(ss, m);
        }
        const float mu  = sm * (1.0f / 128.0f);
        const float var = ss * (1.0f / 128.0f) - mu * mu;
        const float rs  = rsqrtf(var + EPS);
        const int   gm  = kgrp * 4 + r;
        #pragma unroll
        for (int t = 0; t < 8; ++t) {
            float z = (acc[t][r] - mu) * rs * gf[t] + bf_[t];
            z = fmaxf(z, 0.f);
            zt[wave][gm][t * 16 + row16] = f2b(z);
        }
    }
    __syncthreads();

    bf16x8 afrag2[4];
    #pragma unroll
    for (int kk = 0; kk < 4; ++kk)
        afrag2[kk] = *reinterpret_cast<const bf16x8*>(&zt[wave][row16][kk * 32 + kgrp * 8]);

    f32x4 acc2[8];
    #pragma unroll
    for (int t = 0; t < 8; ++t) acc2[t] = (f32x4){0.f, 0.f, 0.f, 0.f};
    #pragma unroll
    for (int t = 0; t < 8; ++t) {
        const float* wp = W2 + (size_t)(t * 16 + row16) * DIM + kgrp * 8;
        #pragma unroll
        for (int kk = 0; kk < 4; ++kk) {
            bf16x8 bfrag = ldw8(wp + kk * 32);
            acc2[t] = __builtin_amdgcn_mfma_f32_16x16x32_bf16(afrag2[kk], bfrag, acc2[t], 0, 0, 0);
        }
    }

    #pragma unroll
    for (int r = 0; r < 4; ++r) {
        float* op = vn_out + (size_t)(gtile * 16 + kgrp * 4 + r) * DIM + row16;
        #pragma unroll
        for (int t = 0; t < 8; ++t)
            op[t * 16] = acc2[t][r] + b2f8[t];
    }
}

// ---------------------------------------------------------------------------
// K3: h_out = h + vn_out[batch], reversed narrow sweep (freshest-L3-first
// after the pool's ascending pass; h ~= L3 capacity). NT stores keep the
// write stream from evicting h.
// ---------------------------------------------------------------------------
__global__ __launch_bounds__(256) void k_add(
    const float* __restrict__ h, const int* __restrict__ batch,
    const float* __restrict__ vn_out, float* __restrict__ h_out,
    int n_nodes)
{
    const long total = (long)n_nodes * 16;     // 16 8-float units per row
    const long GS    = (long)gridDim.x * blockDim.x;
    const long gtid  = (long)blockIdx.x * blockDim.x + threadIdx.x;
    for (long base = ((total + GS - 1) / GS - 1) * GS; base >= 0; base -= GS) {
        const long u = base + gtid;
        if (u >= total) continue;
        const int n = (int)(u >> 4);
        const int c = ((int)u & 15) * 8;
        const float* hp = h + (size_t)n * DIM + c;
        f32x4 h0 = *reinterpret_cast<const f32x4*>(hp);
        f32x4 h1 = *reinterpret_cast<const f32x4*>(hp + 4);
        const int b = batch[n];
        const float* vp = vn_out + (size_t)b * DIM + c;
        f32x4 v0 = *reinterpret_cast<const f32x4*>(vp);
        f32x4 v1 = *reinterpret_cast<const f32x4*>(vp + 4);
        float* op = h_out + (size_t)n * DIM + c;
        __builtin_nontemporal_store(h0 + v0, reinterpret_cast<f32x4*>(op));
        __builtin_nontemporal_store(h1 + v1, reinterpret_cast<f32x4*>(op + 4));
    }
}

// ---------------------------------------------------------------------------
extern "C" void kernel_launch(void* const* d_in, const int* in_sizes, int n_in,
                              void* d_out, int out_size, void* d_ws, size_t ws_size,
                              hipStream_t stream)
{
    const float* h    = (const float*)d_in[0];
    const int*   bat  = (const int*)d_in[1];
    const float* vn   = (const float*)d_in[2];
    const float* W1   = (const float*)d_in[3];
    const float* b1   = (const float*)d_in[4];
    const float* lng  = (const float*)d_in[5];
    const float* lnb  = (const float*)d_in[6];
    const float* W2   = (const float*)d_in[7];
    const float* b2v  = (const float*)d_in[8];

    const int n_nodes = in_sizes[0] / DIM;   // 500000
    const int nb      = in_sizes[2] / DIM;   // 8192

    float* out    = (float*)d_out;           // f32 output buffer
    float* h_out  = out;
    float* vn_out = out + (size_t)n_nodes * DIM;
    float* accum  = out;                     // 4 MB scratch in h_out region
    int*   bounds = (int*)d_ws;              // (nb+1) ints

    k_zero<<<(nb * DIM) / 1024, 256, 0, stream>>>(accum);
    k_bounds<<<(n_nodes + 256) / 256, 256, 0, stream>>>(bat, bounds, n_nodes, nb);
    k_pool_ns<<<1024, 256, 0, stream>>>(h, bat, accum, n_nodes);
    k_mlp<<<nb / 64, 256, 0, stream>>>(accum, bounds, vn, W1, b1, lng, lnb,
                                       W2, b2v, vn_out);
    k_add<<<2048, 256, 0, stream>>>(h, bat, vn_out, h_out, n_nodes);
}

// Round 12
// 155.955 us; speedup vs baseline: 2.9695x; 1.2426x over previous
//
#include <hip/hip_runtime.h>

#define DIM 128
#define EPS 1e-5f

typedef short           bf16x8 __attribute__((ext_vector_type(8)));
typedef unsigned short  u16x8  __attribute__((ext_vector_type(8)));
typedef float           f32x4  __attribute__((ext_vector_type(4)));

__device__ __forceinline__ unsigned short f2b(float f) {
    unsigned int u = __builtin_bit_cast(unsigned int, f);
    unsigned int r = (u + 0x7FFFu + ((u >> 16) & 1u)) >> 16;   // RNE
    return (unsigned short)r;
}
__device__ __forceinline__ bf16x8 ldw8(const float* __restrict__ p) {
    f32x4 a = *reinterpret_cast<const f32x4*>(p);
    f32x4 b = *reinterpret_cast<const f32x4*>(p + 4);
    bf16x8 r;
    #pragma unroll
    for (int j = 0; j < 4; ++j) {
        r[j]     = (short)f2b(a[j]);
        r[j + 4] = (short)f2b(b[j]);
    }
    return r;
}

// ---------------------------------------------------------------------------
// K0: segment boundaries. bounds[b] = first n with batch[n] >= b.
// ---------------------------------------------------------------------------
__global__ __launch_bounds__(256) void k_bounds(
    const int* __restrict__ batch, int* __restrict__ bounds, int n_nodes, int nb)
{
    const int idx = blockIdx.x * blockDim.x + threadIdx.x;
    if (idx > n_nodes) return;
    const int cur  = (idx < n_nodes) ? batch[idx] : nb;
    const int prev = (idx > 0) ? batch[idx - 1] : -1;
    for (int b = prev + 1; b <= cur; ++b) bounds[b] = idx;
}

// ---------------------------------------------------------------------------
// K1 (R4's proven kernel + precomputed bounds): pool 16 graphs per block +
// vn_h add + 2-layer MFMA MLP. 256 threads = 16 graphs x 16 lanes; register
// segment accumulate; wave 0 runs the MLP; vn_out written f32.
// ---------------------------------------------------------------------------
__global__ __launch_bounds__(256) void k_pool_mlp(
    const float* __restrict__ h, const int* __restrict__ bounds,
    const float* __restrict__ vn,
    const float* __restrict__ W1, const float* __restrict__ b1,
    const float* __restrict__ lng, const float* __restrict__ lnb,
    const float* __restrict__ W2, const float* __restrict__ b2v,
    float* __restrict__ vn_out, int n_nodes)
{
    __shared__ int sb[17];
    __shared__ unsigned short xtile[16][136];   // bf16 MLP input tile (padded)

    const int tid = threadIdx.x;
    const int G0  = blockIdx.x * 16;

    if (tid < 17) sb[tid] = bounds[G0 + tid];
    __syncthreads();

    const int gi = tid >> 4;    // graph within tile (0..15)
    const int j  = tid & 15;    // 8-feature slot
    const int s = sb[gi], e = sb[gi + 1];

    // ---- register-accumulated segment pool ----
    f32x4 a0 = (f32x4){0.f, 0.f, 0.f, 0.f};
    f32x4 a1 = (f32x4){0.f, 0.f, 0.f, 0.f};
    for (int n = s; n < e; ++n) {
        const float* p = h + (size_t)n * DIM + j * 8;
        a0 += *reinterpret_cast<const f32x4*>(p);
        a1 += *reinterpret_cast<const f32x4*>(p + 4);
    }
    const int cnt = e - s;
    const float inv = 1.0f / (float)(cnt > 1 ? cnt : 1);
    const float* vp = vn + (size_t)(G0 + gi) * DIM + j * 8;
    f32x4 v0 = *reinterpret_cast<const f32x4*>(vp);
    f32x4 v1 = *reinterpret_cast<const f32x4*>(vp + 4);
    u16x8 xv;
    #pragma unroll
    for (int q = 0; q < 4; ++q) {
        xv[q]     = f2b(fmaf(a0[q], inv, v0[q]));
        xv[q + 4] = f2b(fmaf(a1[q], inv, v1[q]));
    }
    *reinterpret_cast<u16x8*>(&xtile[gi][j * 8]) = xv;
    __syncthreads();

    // ---- wave 0: 2-layer MFMA MLP ----
    // A/B share the element->k bijection -> k-permutation safe.
    // C/D (m89-verified): col n = lane&15, row m = (lane>>4)*4 + reg.
    if (tid < 64) {
        const int row16 = tid & 15;
        const int kgrp  = tid >> 4;

        bf16x8 afrag[4];
        #pragma unroll
        for (int kk = 0; kk < 4; ++kk)
            afrag[kk] = *reinterpret_cast<const bf16x8*>(&xtile[row16][kgrp * 8 + kk * 32]);

        f32x4 acc[8];
        #pragma unroll
        for (int t = 0; t < 8; ++t) acc[t] = (f32x4){0.f, 0.f, 0.f, 0.f};
        #pragma unroll
        for (int t = 0; t < 8; ++t) {
            const float* wp = W1 + (size_t)(t * 16 + row16) * DIM + kgrp * 8;
            #pragma unroll
            for (int kk = 0; kk < 4; ++kk) {
                bf16x8 bfrag = ldw8(wp + kk * 32);
                acc[t] = __builtin_amdgcn_mfma_f32_16x16x32_bf16(afrag[kk], bfrag, acc[t], 0, 0, 0);
            }
        }

        float b1f[8], gf[8], bf_[8], b2f8[8];
        #pragma unroll
        for (int t = 0; t < 8; ++t) {
            const int f = t * 16 + row16;
            b1f[t]  = b1[f];
            gf[t]   = lng[f];
            bf_[t]  = lnb[f];
            b2f8[t] = b2v[f];
        }
        #pragma unroll
        for (int t = 0; t < 8; ++t)
            #pragma unroll
            for (int r = 0; r < 4; ++r) acc[t][r] += b1f[t];

        // LayerNorm + ReLU -> z (bf16) back into xtile
        #pragma unroll
        for (int r = 0; r < 4; ++r) {
            float sm = 0.f, ss = 0.f;
            #pragma unroll
            for (int t = 0; t < 8; ++t) { sm += acc[t][r]; ss += acc[t][r] * acc[t][r]; }
            #pragma unroll
            for (int m = 1; m <= 8; m <<= 1) {
                sm += __shfl_xor(sm, m);
                ss += __shfl_xor(ss, m);
            }
            const float mu  = sm * (1.0f / 128.0f);
            const float var = ss * (1.0f / 128.0f) - mu * mu;
            const float rs  = rsqrtf(var + EPS);
            const int   gm  = kgrp * 4 + r;
            #pragma unroll
            for (int t = 0; t < 8; ++t) {
                float z = (acc[t][r] - mu) * rs * gf[t] + bf_[t];
                z = fmaxf(z, 0.f);
                xtile[gm][t * 16 + row16] = f2b(z);
            }
        }
        // wave-internal LDS ordering: reads below see this wave's writes

        bf16x8 afrag2[4];
        #pragma unroll
        for (int kk = 0; kk < 4; ++kk)
            afrag2[kk] = *reinterpret_cast<const bf16x8*>(&xtile[row16][kgrp * 8 + kk * 32]);

        f32x4 acc2[8];
        #pragma unroll
        for (int t = 0; t < 8; ++t) acc2[t] = (f32x4){0.f, 0.f, 0.f, 0.f};
        #pragma unroll
        for (int t = 0; t < 8; ++t) {
            const float* wp = W2 + (size_t)(t * 16 + row16) * DIM + kgrp * 8;
            #pragma unroll
            for (int kk = 0; kk < 4; ++kk) {
                bf16x8 bfrag = ldw8(wp + kk * 32);
                acc2[t] = __builtin_amdgcn_mfma_f32_16x16x32_bf16(afrag2[kk], bfrag, acc2[t], 0, 0, 0);
            }
        }

        #pragma unroll
        for (int r = 0; r < 4; ++r) {
            float* op = vn_out + (size_t)(G0 + kgrp * 4 + r) * DIM + row16;
            #pragma unroll
            for (int t = 0; t < 8; ++t)
                op[t * 16] = acc2[t][r] + b2f8[t];
        }
    }
}

// ---------------------------------------------------------------------------
// K2: h_out = h + vn_out[batch], REVERSE sliding-window sweep.
// After k_pool_mlp's forward sweep L3 holds h tail-freshest; reading
// tail-first under ~LRU turns the re-read into L3 hits. NT stores keep the
// h_out write stream from evicting h. (Only change vs R4: direction.)
// ---------------------------------------------------------------------------
__global__ __launch_bounds__(256) void k_add(
    const float* __restrict__ h, const int* __restrict__ batch,
    const float* __restrict__ vn_out, float* __restrict__ h_out,
    int n_nodes)
{
    const long total = (long)n_nodes * 16;     // 16 8-float units per row
    const long GS    = (long)gridDim.x * blockDim.x;
    const long gtid  = (long)blockIdx.x * blockDim.x + threadIdx.x;
    for (long base = ((total + GS - 1) / GS - 1) * GS; base >= 0; base -= GS) {
        const long u = base + gtid;
        if (u >= total) continue;
        const int n = (int)(u >> 4);
        const int c = ((int)u & 15) * 8;
        const float* hp = h + (size_t)n * DIM + c;
        f32x4 h0 = *reinterpret_cast<const f32x4*>(hp);
        f32x4 h1 = *reinterpret_cast<const f32x4*>(hp + 4);
        const int b = batch[n];
        const float* vp = vn_out + (size_t)b * DIM + c;
        f32x4 v0 = *reinterpret_cast<const f32x4*>(vp);
        f32x4 v1 = *reinterpret_cast<const f32x4*>(vp + 4);
        float* op = h_out + (size_t)n * DIM + c;
        __builtin_nontemporal_store(h0 + v0, reinterpret_cast<f32x4*>(op));
        __builtin_nontemporal_store(h1 + v1, reinterpret_cast<f32x4*>(op + 4));
    }
}

// ---------------------------------------------------------------------------
extern "C" void kernel_launch(void* const* d_in, const int* in_sizes, int n_in,
                              void* d_out, int out_size, void* d_ws, size_t ws_size,
                              hipStream_t stream)
{
    const float* h    = (const float*)d_in[0];
    const int*   bat  = (const int*)d_in[1];
    const float* vn   = (const float*)d_in[2];
    const float* W1   = (const float*)d_in[3];
    const float* b1   = (const float*)d_in[4];
    const float* lng  = (const float*)d_in[5];
    const float* lnb  = (const float*)d_in[6];
    const float* W2   = (const float*)d_in[7];
    const float* b2v  = (const float*)d_in[8];

    const int n_nodes = in_sizes[0] / DIM;   // 500000
    const int nb      = in_sizes[2] / DIM;   // 8192

    float* out    = (float*)d_out;           // f32 output buffer
    float* h_out  = out;
    float* vn_out = out + (size_t)n_nodes * DIM;
    int*   bounds = (int*)d_ws;              // (nb+1) ints

    k_bounds<<<(n_nodes + 256) / 256, 256, 0, stream>>>(bat, bounds, n_nodes, nb);
    k_pool_mlp<<<nb / 16, 256, 0, stream>>>(h, bounds, vn, W1, b1, lng, lnb,
                                            W2, b2v, vn_out, n_nodes);
    k_add<<<2048, 256, 0, stream>>>(h, bat, vn_out, h_out, n_nodes);
}